// Round 1
// baseline (740.364 us; speedup 1.0000x reference)
//
#include <hip/hip_runtime.h>

#define HW     784
#define HW4    196                 // HW / 4 (float4 per channel row)
#define CIN    4096
#define COUT   4
#define NIMG   32
#define CCHUNK 128
#define NCHUNK (CIN / CCHUNK)      // 32
#define F4_PER_IMG (CIN * HW4)     // 802816

__device__ __forceinline__ float4 f4zero() { return make_float4(0.f, 0.f, 0.f, 0.f); }

// ---------------------------------------------------------------------------
// k1: per (image, channel-chunk) partial CAM sums.
//   PARTIAL path: plain float4 stores into part[n][cc][o][hw4]  (no atomics,
//                 no memset — every element written).
//   ATOMIC  path: fallback when ws too small — atomicAdd into cams_raw[n][o][hw].
// ---------------------------------------------------------------------------
template <bool ATOMIC>
__global__ __launch_bounds__(256) void k1_cams(const float4* __restrict__ x4,
                                               const float*  __restrict__ w,
                                               float*        __restrict__ outbuf) {
    const int n  = blockIdx.x;   // image
    const int cc = blockIdx.y;   // channel chunk
    const int t  = threadIdx.x;  // 0..255

    __shared__ float4 wlds[CCHUNK];          // packed (w0,w1,w2,w3) per channel
    if (t < CCHUNK) {
        const int c = cc * CCHUNK + t;
        wlds[t] = make_float4(w[0 * CIN + c], w[1 * CIN + c],
                              w[2 * CIN + c], w[3 * CIN + c]);
    }
    __syncthreads();
    if (t >= HW4) return;                    // lanes 196..255 idle (no later barrier)

    const float4* xp = x4 + ((size_t)n * CIN + (size_t)cc * CCHUNK) * HW4 + t;

    float4 a0 = f4zero(), a1 = f4zero(), a2 = f4zero(), a3 = f4zero();
    #pragma unroll 8
    for (int c = 0; c < CCHUNK; ++c) {
        float4 xv = xp[(size_t)c * HW4];     // one global_load_dwordx4 / channel
        float4 wv = wlds[c];                 // one broadcast ds_read_b128
        a0.x += xv.x * wv.x; a0.y += xv.y * wv.x; a0.z += xv.z * wv.x; a0.w += xv.w * wv.x;
        a1.x += xv.x * wv.y; a1.y += xv.y * wv.y; a1.z += xv.z * wv.y; a1.w += xv.w * wv.y;
        a2.x += xv.x * wv.z; a2.y += xv.y * wv.z; a2.z += xv.z * wv.z; a2.w += xv.w * wv.z;
        a3.x += xv.x * wv.w; a3.y += xv.y * wv.w; a3.z += xv.z * wv.w; a3.w += xv.w * wv.w;
    }

    if constexpr (ATOMIC) {
        float* cp = outbuf + (size_t)n * COUT * HW + 4 * t;
        atomicAdd(&cp[0 * HW + 0], a0.x); atomicAdd(&cp[0 * HW + 1], a0.y);
        atomicAdd(&cp[0 * HW + 2], a0.z); atomicAdd(&cp[0 * HW + 3], a0.w);
        atomicAdd(&cp[1 * HW + 0], a1.x); atomicAdd(&cp[1 * HW + 1], a1.y);
        atomicAdd(&cp[1 * HW + 2], a1.z); atomicAdd(&cp[1 * HW + 3], a1.w);
        atomicAdd(&cp[2 * HW + 0], a2.x); atomicAdd(&cp[2 * HW + 1], a2.y);
        atomicAdd(&cp[2 * HW + 2], a2.z); atomicAdd(&cp[2 * HW + 3], a2.w);
        atomicAdd(&cp[3 * HW + 0], a3.x); atomicAdd(&cp[3 * HW + 1], a3.y);
        atomicAdd(&cp[3 * HW + 2], a3.z); atomicAdd(&cp[3 * HW + 3], a3.w);
    } else {
        float4* pp = (float4*)outbuf +
                     (((size_t)n * NCHUNK + cc) * COUT) * HW4 + t;
        pp[0 * HW4] = a0;
        pp[1 * HW4] = a1;
        pp[2 * HW4] = a2;
        pp[3 * HW4] = a3;
    }
}

// ---------------------------------------------------------------------------
// k2: reduce P partial slabs -> relu -> per-(n,o) max -> threshold -> s[n][hw]
//   part layout: [n][p][o][hw4] float4;  P = NCHUNK (partial path) or 1 (atomic).
// ---------------------------------------------------------------------------
__global__ __launch_bounds__(256) void k2_scale(const float4* __restrict__ part,
                                                int P,
                                                const float* __restrict__ gama_p,
                                                float* __restrict__ s) {
    const int n = blockIdx.x;
    const int t = threadIdx.x;
    const float gama = gama_p[0];

    float4 c0 = f4zero(), c1 = f4zero(), c2 = f4zero(), c3 = f4zero();
    if (t < HW4) {
        for (int p = 0; p < P; ++p) {
            const float4* pp = part + ((size_t)(n * P + p) * COUT) * HW4 + t;
            float4 v0 = pp[0 * HW4], v1 = pp[1 * HW4], v2 = pp[2 * HW4], v3 = pp[3 * HW4];
            c0.x += v0.x; c0.y += v0.y; c0.z += v0.z; c0.w += v0.w;
            c1.x += v1.x; c1.y += v1.y; c1.z += v1.z; c1.w += v1.w;
            c2.x += v2.x; c2.y += v2.y; c2.z += v2.z; c2.w += v2.w;
            c3.x += v3.x; c3.y += v3.y; c3.z += v3.z; c3.w += v3.w;
        }
    }
    // relu
    c0.x = fmaxf(c0.x, 0.f); c0.y = fmaxf(c0.y, 0.f); c0.z = fmaxf(c0.z, 0.f); c0.w = fmaxf(c0.w, 0.f);
    c1.x = fmaxf(c1.x, 0.f); c1.y = fmaxf(c1.y, 0.f); c1.z = fmaxf(c1.z, 0.f); c1.w = fmaxf(c1.w, 0.f);
    c2.x = fmaxf(c2.x, 0.f); c2.y = fmaxf(c2.y, 0.f); c2.z = fmaxf(c2.z, 0.f); c2.w = fmaxf(c2.w, 0.f);
    c3.x = fmaxf(c3.x, 0.f); c3.y = fmaxf(c3.y, 0.f); c3.z = fmaxf(c3.z, 0.f); c3.w = fmaxf(c3.w, 0.f);

    __shared__ float red[COUT][256];
    red[0][t] = (t < HW4) ? fmaxf(fmaxf(c0.x, c0.y), fmaxf(c0.z, c0.w)) : 0.f;
    red[1][t] = (t < HW4) ? fmaxf(fmaxf(c1.x, c1.y), fmaxf(c1.z, c1.w)) : 0.f;
    red[2][t] = (t < HW4) ? fmaxf(fmaxf(c2.x, c2.y), fmaxf(c2.z, c2.w)) : 0.f;
    red[3][t] = (t < HW4) ? fmaxf(fmaxf(c3.x, c3.y), fmaxf(c3.z, c3.w)) : 0.f;
    __syncthreads();
    for (int str = 128; str > 0; str >>= 1) {
        if (t < str) {
            #pragma unroll
            for (int o = 0; o < COUT; ++o)
                red[o][t] = fmaxf(red[o][t], red[o][t + str]);
        }
        __syncthreads();
    }
    const float t0 = red[0][0] * gama;
    const float t1 = red[1][0] * gama;
    const float t2 = red[2][0] * gama;
    const float t3 = red[3][0] * gama;

    if (t < HW4) {
        float4 sv;
        sv.x = (((c0.x > t0) ? 0.f : c0.x) + ((c1.x > t1) ? 0.f : c1.x) +
                ((c2.x > t2) ? 0.f : c2.x) + ((c3.x > t3) ? 0.f : c3.x)) * 0.25f;
        sv.y = (((c0.y > t0) ? 0.f : c0.y) + ((c1.y > t1) ? 0.f : c1.y) +
                ((c2.y > t2) ? 0.f : c2.y) + ((c3.y > t3) ? 0.f : c3.y)) * 0.25f;
        sv.z = (((c0.z > t0) ? 0.f : c0.z) + ((c1.z > t1) ? 0.f : c1.z) +
                ((c2.z > t2) ? 0.f : c2.z) + ((c3.z > t3) ? 0.f : c3.z)) * 0.25f;
        sv.w = (((c0.w > t0) ? 0.f : c0.w) + ((c1.w > t1) ? 0.f : c1.w) +
                ((c2.w > t2) ? 0.f : c2.w) + ((c3.w > t3) ? 0.f : c3.w)) * 0.25f;
        ((float4*)(s + (size_t)n * HW))[t] = sv;
    }
}

// ---------------------------------------------------------------------------
// k3: out = x * s  (float4 streaming)
// ---------------------------------------------------------------------------
__global__ __launch_bounds__(256) void k3_mul(const float4* __restrict__ x4,
                                              const float* __restrict__ s,
                                              float4* __restrict__ out4) {
    const int n = blockIdx.y;
    const int g = blockIdx.x * 256 + threadIdx.x;  // 0 .. F4_PER_IMG-1
    const int hw4 = g % HW4;
    const size_t idx = (size_t)n * F4_PER_IMG + g;
    float4 xv = x4[idx];
    const float4* s4 = (const float4*)(s + (size_t)n * HW);
    float4 sv = s4[hw4];
    float4 ov;
    ov.x = xv.x * sv.x;
    ov.y = xv.y * sv.y;
    ov.z = xv.z * sv.z;
    ov.w = xv.w * sv.w;
    out4[idx] = ov;
}

extern "C" void kernel_launch(void* const* d_in, const int* in_sizes, int n_in,
                              void* d_out, int out_size, void* d_ws, size_t ws_size,
                              hipStream_t stream) {
    const float* x    = (const float*)d_in[0];
    const float* w    = (const float*)d_in[1];
    const float* gama = (const float*)d_in[2];
    float* out = (float*)d_out;

    const size_t part_floats = (size_t)NIMG * NCHUNK * COUT * HW;   // 3.2M floats
    const size_t s_floats    = (size_t)NIMG * HW;
    const bool use_partials  = ws_size >= (part_floats + s_floats) * sizeof(float);

    if (use_partials) {
        float* part = (float*)d_ws;
        float* s    = part + part_floats;
        k1_cams<false><<<dim3(NIMG, NCHUNK), 256, 0, stream>>>(
            (const float4*)x, w, part);
        k2_scale<<<NIMG, 256, 0, stream>>>((const float4*)part, NCHUNK, gama, s);
        k3_mul<<<dim3(F4_PER_IMG / 256, NIMG), 256, 0, stream>>>(
            (const float4*)x, s, (float4*)out);
    } else {
        float* cams_raw = (float*)d_ws;
        float* s        = cams_raw + (size_t)NIMG * COUT * HW;
        hipMemsetAsync(cams_raw, 0, (size_t)NIMG * COUT * HW * sizeof(float), stream);
        k1_cams<true><<<dim3(NIMG, NCHUNK), 256, 0, stream>>>(
            (const float4*)x, w, cams_raw);
        k2_scale<<<NIMG, 256, 0, stream>>>((const float4*)cams_raw, 1, gama, s);
        k3_mul<<<dim3(F4_PER_IMG / 256, NIMG), 256, 0, stream>>>(
            (const float4*)x, s, (float4*)out);
    }
}

// Round 3
// 730.033 us; speedup vs baseline: 1.0142x; 1.0142x over previous
//
#include <hip/hip_runtime.h>

#define HW     784
#define HW4    196                 // HW / 4 (float4 per channel row)
#define CIN    4096
#define COUT   4
#define NIMG   32
#define CCHUNK 128
#define NCHUNK (CIN / CCHUNK)      // 32
#define F4_PER_IMG (CIN * HW4)     // 802816
#define K3_SUB (CCHUNK * HW4 / 256)   // 98 blocks per (image, chunk)

typedef float f4raw __attribute__((ext_vector_type(4)));  // native vec for nontemporal builtins

__device__ __forceinline__ float4 f4zero() { return make_float4(0.f, 0.f, 0.f, 0.f); }

// ---------------------------------------------------------------------------
// k1: per (image, channel-chunk) partial CAM sums.
//   PARTIAL path: plain float4 stores into part[n][cc][o][hw4]  (no atomics,
//                 no memset — every element written).
//   ATOMIC  path: fallback when ws too small — atomicAdd into cams_raw[n][o][hw].
//   x loads are REGULAR (we want x resident in L3 for k3's re-read).
//   Temporal order of grid: blockIdx.x = n (fast), blockIdx.y = cc (slow)
//   => last-read data = high cc chunks for all images.  k3 reverses this.
// ---------------------------------------------------------------------------
template <bool ATOMIC>
__global__ __launch_bounds__(256) void k1_cams(const float4* __restrict__ x4,
                                               const float*  __restrict__ w,
                                               float*        __restrict__ outbuf) {
    const int n  = blockIdx.x;   // image
    const int cc = blockIdx.y;   // channel chunk
    const int t  = threadIdx.x;  // 0..255

    __shared__ float4 wlds[CCHUNK];          // packed (w0,w1,w2,w3) per channel
    if (t < CCHUNK) {
        const int c = cc * CCHUNK + t;
        wlds[t] = make_float4(w[0 * CIN + c], w[1 * CIN + c],
                              w[2 * CIN + c], w[3 * CIN + c]);
    }
    __syncthreads();
    if (t >= HW4) return;                    // lanes 196..255 idle (no later barrier)

    const float4* xp = x4 + ((size_t)n * CIN + (size_t)cc * CCHUNK) * HW4 + t;

    float4 a0 = f4zero(), a1 = f4zero(), a2 = f4zero(), a3 = f4zero();
    #pragma unroll 8
    for (int c = 0; c < CCHUNK; ++c) {
        float4 xv = xp[(size_t)c * HW4];     // one global_load_dwordx4 / channel
        float4 wv = wlds[c];                 // one broadcast ds_read_b128
        a0.x += xv.x * wv.x; a0.y += xv.y * wv.x; a0.z += xv.z * wv.x; a0.w += xv.w * wv.x;
        a1.x += xv.x * wv.y; a1.y += xv.y * wv.y; a1.z += xv.z * wv.y; a1.w += xv.w * wv.y;
        a2.x += xv.x * wv.z; a2.y += xv.y * wv.z; a2.z += xv.z * wv.z; a2.w += xv.w * wv.z;
        a3.x += xv.x * wv.w; a3.y += xv.y * wv.w; a3.z += xv.z * wv.w; a3.w += xv.w * wv.w;
    }

    if constexpr (ATOMIC) {
        float* cp = outbuf + (size_t)n * COUT * HW + 4 * t;
        atomicAdd(&cp[0 * HW + 0], a0.x); atomicAdd(&cp[0 * HW + 1], a0.y);
        atomicAdd(&cp[0 * HW + 2], a0.z); atomicAdd(&cp[0 * HW + 3], a0.w);
        atomicAdd(&cp[1 * HW + 0], a1.x); atomicAdd(&cp[1 * HW + 1], a1.y);
        atomicAdd(&cp[1 * HW + 2], a1.z); atomicAdd(&cp[1 * HW + 3], a1.w);
        atomicAdd(&cp[2 * HW + 0], a2.x); atomicAdd(&cp[2 * HW + 1], a2.y);
        atomicAdd(&cp[2 * HW + 2], a2.z); atomicAdd(&cp[2 * HW + 3], a2.w);
        atomicAdd(&cp[3 * HW + 0], a3.x); atomicAdd(&cp[3 * HW + 1], a3.y);
        atomicAdd(&cp[3 * HW + 2], a3.z); atomicAdd(&cp[3 * HW + 3], a3.w);
    } else {
        float4* pp = (float4*)outbuf +
                     (((size_t)n * NCHUNK + cc) * COUT) * HW4 + t;
        pp[0 * HW4] = a0;
        pp[1 * HW4] = a1;
        pp[2 * HW4] = a2;
        pp[3 * HW4] = a3;
    }
}

// ---------------------------------------------------------------------------
// k2: reduce P partial slabs -> relu -> per-(n,o) max -> threshold -> s[n][hw]
//   part layout: [n][p][o][hw4] float4;  P = NCHUNK (partial path) or 1 (atomic).
// ---------------------------------------------------------------------------
__global__ __launch_bounds__(256) void k2_scale(const float4* __restrict__ part,
                                                int P,
                                                const float* __restrict__ gama_p,
                                                float* __restrict__ s) {
    const int n = blockIdx.x;
    const int t = threadIdx.x;
    const float gama = gama_p[0];

    float4 c0 = f4zero(), c1 = f4zero(), c2 = f4zero(), c3 = f4zero();
    if (t < HW4) {
        for (int p = 0; p < P; ++p) {
            const float4* pp = part + ((size_t)(n * P + p) * COUT) * HW4 + t;
            float4 v0 = pp[0 * HW4], v1 = pp[1 * HW4], v2 = pp[2 * HW4], v3 = pp[3 * HW4];
            c0.x += v0.x; c0.y += v0.y; c0.z += v0.z; c0.w += v0.w;
            c1.x += v1.x; c1.y += v1.y; c1.z += v1.z; c1.w += v1.w;
            c2.x += v2.x; c2.y += v2.y; c2.z += v2.z; c2.w += v2.w;
            c3.x += v3.x; c3.y += v3.y; c3.z += v3.z; c3.w += v3.w;
        }
    }
    // relu
    c0.x = fmaxf(c0.x, 0.f); c0.y = fmaxf(c0.y, 0.f); c0.z = fmaxf(c0.z, 0.f); c0.w = fmaxf(c0.w, 0.f);
    c1.x = fmaxf(c1.x, 0.f); c1.y = fmaxf(c1.y, 0.f); c1.z = fmaxf(c1.z, 0.f); c1.w = fmaxf(c1.w, 0.f);
    c2.x = fmaxf(c2.x, 0.f); c2.y = fmaxf(c2.y, 0.f); c2.z = fmaxf(c2.z, 0.f); c2.w = fmaxf(c2.w, 0.f);
    c3.x = fmaxf(c3.x, 0.f); c3.y = fmaxf(c3.y, 0.f); c3.z = fmaxf(c3.z, 0.f); c3.w = fmaxf(c3.w, 0.f);

    __shared__ float red[COUT][256];
    red[0][t] = (t < HW4) ? fmaxf(fmaxf(c0.x, c0.y), fmaxf(c0.z, c0.w)) : 0.f;
    red[1][t] = (t < HW4) ? fmaxf(fmaxf(c1.x, c1.y), fmaxf(c1.z, c1.w)) : 0.f;
    red[2][t] = (t < HW4) ? fmaxf(fmaxf(c2.x, c2.y), fmaxf(c2.z, c2.w)) : 0.f;
    red[3][t] = (t < HW4) ? fmaxf(fmaxf(c3.x, c3.y), fmaxf(c3.z, c3.w)) : 0.f;
    __syncthreads();
    for (int str = 128; str > 0; str >>= 1) {
        if (t < str) {
            #pragma unroll
            for (int o = 0; o < COUT; ++o)
                red[o][t] = fmaxf(red[o][t], red[o][t + str]);
        }
        __syncthreads();
    }
    const float t0 = red[0][0] * gama;
    const float t1 = red[1][0] * gama;
    const float t2 = red[2][0] * gama;
    const float t3 = red[3][0] * gama;

    if (t < HW4) {
        float4 sv;
        sv.x = (((c0.x > t0) ? 0.f : c0.x) + ((c1.x > t1) ? 0.f : c1.x) +
                ((c2.x > t2) ? 0.f : c2.x) + ((c3.x > t3) ? 0.f : c3.x)) * 0.25f;
        sv.y = (((c0.y > t0) ? 0.f : c0.y) + ((c1.y > t1) ? 0.f : c1.y) +
                ((c2.y > t2) ? 0.f : c2.y) + ((c3.y > t3) ? 0.f : c3.y)) * 0.25f;
        sv.z = (((c0.z > t0) ? 0.f : c0.z) + ((c1.z > t1) ? 0.f : c1.z) +
                ((c2.z > t2) ? 0.f : c2.z) + ((c3.z > t3) ? 0.f : c3.z)) * 0.25f;
        sv.w = (((c0.w > t0) ? 0.f : c0.w) + ((c1.w > t1) ? 0.f : c1.w) +
                ((c2.w > t2) ? 0.f : c2.w) + ((c3.w > t3) ? 0.f : c3.w)) * 0.25f;
        ((float4*)(s + (size_t)n * HW))[t] = sv;
    }
}

// ---------------------------------------------------------------------------
// k3: out = x * s  (float4 streaming)
//   Block order REVERSES k1's temporal order: cc descending (slow), image
//   (mid), sub-block (fast).  The first ~250 MB k3 reads are exactly the last
//   ~250 MB k1 read => served by Infinity Cache instead of HBM.
//   x loads and out stores are NONTEMPORAL (via ext_vector_type — the builtin
//   rejects HIP_vector_type) so this one-time stream does not evict the
//   resident x working set from L3.
// ---------------------------------------------------------------------------
__global__ __launch_bounds__(256) void k3_mul(const f4raw* __restrict__ x4,
                                              const float* __restrict__ s,
                                              f4raw* __restrict__ out4) {
    const int bid   = blockIdx.x;                 // 0 .. NCHUNK*NIMG*K3_SUB-1
    const int ccRev = bid / (NIMG * K3_SUB);
    const int rem   = bid % (NIMG * K3_SUB);
    const int n     = rem / K3_SUB;
    const int sub   = rem % K3_SUB;
    const int cc    = NCHUNK - 1 - ccRev;         // descending chunks

    const int f4InImg = cc * (CCHUNK * HW4) + sub * 256 + threadIdx.x;
    const int hw4     = f4InImg % HW4;
    const size_t idx  = (size_t)n * F4_PER_IMG + f4InImg;

    f4raw xv = __builtin_nontemporal_load(&x4[idx]);
    const f4raw* s4 = (const f4raw*)(s + (size_t)n * HW);
    f4raw sv = s4[hw4];
    f4raw ov = xv * sv;
    __builtin_nontemporal_store(ov, &out4[idx]);
}

extern "C" void kernel_launch(void* const* d_in, const int* in_sizes, int n_in,
                              void* d_out, int out_size, void* d_ws, size_t ws_size,
                              hipStream_t stream) {
    const float* x    = (const float*)d_in[0];
    const float* w    = (const float*)d_in[1];
    const float* gama = (const float*)d_in[2];
    float* out = (float*)d_out;

    const size_t part_floats = (size_t)NIMG * NCHUNK * COUT * HW;   // 3.2M floats
    const size_t s_floats    = (size_t)NIMG * HW;
    const bool use_partials  = ws_size >= (part_floats + s_floats) * sizeof(float);

    if (use_partials) {
        float* part = (float*)d_ws;
        float* s    = part + part_floats;
        k1_cams<false><<<dim3(NIMG, NCHUNK), 256, 0, stream>>>(
            (const float4*)x, w, part);
        k2_scale<<<NIMG, 256, 0, stream>>>((const float4*)part, NCHUNK, gama, s);
        k3_mul<<<NCHUNK * NIMG * K3_SUB, 256, 0, stream>>>(
            (const f4raw*)x, s, (f4raw*)out);
    } else {
        float* cams_raw = (float*)d_ws;
        float* s        = cams_raw + (size_t)NIMG * COUT * HW;
        (void)hipMemsetAsync(cams_raw, 0, (size_t)NIMG * COUT * HW * sizeof(float), stream);
        k1_cams<true><<<dim3(NIMG, NCHUNK), 256, 0, stream>>>(
            (const float4*)x, w, cams_raw);
        k2_scale<<<NIMG, 256, 0, stream>>>((const float4*)cams_raw, 1, gama, s);
        k3_mul<<<NCHUNK * NIMG * K3_SUB, 256, 0, stream>>>(
            (const f4raw*)x, s, (f4raw*)out);
    }
}